// Round 1
// baseline (1306.408 us; speedup 1.0000x reference)
//
#include <hip/hip_runtime.h>
#include <hip/hip_bf16.h>

typedef __hip_bfloat16 bf16;
using bf16x8 = __attribute__((ext_vector_type(8))) __bf16;
using f32x4  = __attribute__((ext_vector_type(4))) float;

#define S_   2048
#define D_   2048
#define H_   16
#define QR_  1536
#define KVR_ 512
#define NOPE_ 128
#define ROPE_ 64
#define VD_  128
#define QKD_ 192
#define EPS_ 1e-5f

// LDS tile row stride (bf16 elems): 32 K + 8 pad -> 80B rows, breaks ds_read_b128 conflicts
#define LSTR 40

// ---------------------------------------------------------------------------
// Generic bf16 MFMA GEMM: C[M,N] = A[M,K] @ B[K,N], B given as BT[N,K].
// block 256 thr = 4 waves; tile 128x128; wave computes 64x64 (4x4 of 16x16).
// mode: 0=f32 store, 1=bf16 store, 2=f32 +res, 3=bf16 gelu(x+bias), 4=f32 +bias+res
// causal: 0=none, 1=skip tiles above diagonal (scores), 2=limit K to diag (PV)
// ---------------------------------------------------------------------------
__global__ __launch_bounds__(256) void gemm_k(
    const bf16* __restrict__ A, const bf16* __restrict__ BT, void* __restrict__ Cv,
    const float* __restrict__ bias, const float* __restrict__ res,
    int M, int N, int K, int lda, int ldb, int ldc,
    long long strideA, long long strideB, long long strideC,
    int mode, int causal)
{
    int bn = blockIdx.x, bm = blockIdx.y, bz = blockIdx.z;
    if (causal == 1 && bn > bm) return;
    A  += (size_t)bz * strideA;
    BT += (size_t)bz * strideB;
    int Keff = K;
    if (causal == 2) { int kl = (bm + 1) * 128; if (kl < Keff) Keff = kl; }

    __shared__ bf16 sA[128 * LSTR];
    __shared__ bf16 sB[128 * LSTR];

    int tid  = threadIdx.x;
    int lane = tid & 63, wave = tid >> 6;
    int wr = wave >> 1, wc = wave & 1;     // wave's 64x64 quadrant
    int fr = lane & 15, fq = lane >> 4;    // fragment row / k-quad

    f32x4 acc[4][4] = {};

    int row0 = bm * 128, col0 = bn * 128;
    int sr  = tid >> 2;          // staging row 0..63
    int sko = (tid & 3) * 8;     // staging k offset {0,8,16,24}

    for (int k0 = 0; k0 < Keff; k0 += 32) {
        // A tile (M is always a multiple of 128 in this problem -> no guard)
        {
            const bf16* ap = A + (size_t)(row0 + sr) * lda + (k0 + sko);
            *(int4*)&sA[sr * LSTR + sko] = *(const int4*)ap;
            *(int4*)&sA[(sr + 64) * LSTR + sko] = *(const int4*)(ap + (size_t)64 * lda);
        }
        // B tile with N guard (N=576 case)
        {
            int gn = col0 + sr;
            int4 v0 = {0,0,0,0}, v1 = {0,0,0,0};
            if (gn < N)      v0 = *(const int4*)(BT + (size_t)gn * ldb + (k0 + sko));
            if (gn + 64 < N) v1 = *(const int4*)(BT + (size_t)(gn + 64) * ldb + (k0 + sko));
            *(int4*)&sB[sr * LSTR + sko] = v0;
            *(int4*)&sB[(sr + 64) * LSTR + sko] = v1;
        }
        __syncthreads();
        bf16x8 af[4], bv[4];
        #pragma unroll
        for (int i = 0; i < 4; ++i)
            af[i] = *(const bf16x8*)&sA[(wr*64 + i*16 + fr) * LSTR + fq*8];
        #pragma unroll
        for (int j = 0; j < 4; ++j)
            bv[j] = *(const bf16x8*)&sB[(wc*64 + j*16 + fr) * LSTR + fq*8];
        #pragma unroll
        for (int i = 0; i < 4; ++i)
            #pragma unroll
            for (int j = 0; j < 4; ++j)
                acc[i][j] = __builtin_amdgcn_mfma_f32_16x16x32_bf16(af[i], bv[j], acc[i][j], 0, 0, 0);
        __syncthreads();
    }

    // epilogue: D[row=(lane>>4)*4+r][col=lane&15] per 16x16 tile (verified m89 layout)
    #pragma unroll
    for (int i = 0; i < 4; ++i) {
        #pragma unroll
        for (int j = 0; j < 4; ++j) {
            int gc = col0 + wc*64 + j*16 + fr;
            if (gc >= N) continue;
            #pragma unroll
            for (int r = 0; r < 4; ++r) {
                int gr = row0 + wr*64 + i*16 + fq*4 + r;
                float v = acc[i][j][r];
                size_t off = (size_t)bz * strideC + (size_t)gr * ldc + gc;
                if (mode == 0) {
                    ((float*)Cv)[off] = v;
                } else if (mode == 1) {
                    ((bf16*)Cv)[off] = __float2bfloat16(v);
                } else if (mode == 2) {
                    ((float*)Cv)[off] = v + res[(size_t)gr * ldc + gc];
                } else if (mode == 3) {
                    float t = v + bias[gc];
                    t = 0.5f * t * (1.0f + erff(t * 0.70710678118654752f));
                    ((bf16*)Cv)[off] = __float2bfloat16(t);
                } else {
                    ((float*)Cv)[off] = v + bias[gc] + res[(size_t)gr * ldc + gc];
                }
            }
        }
    }
}

// ---------------------------------------------------------------------------
// Weight transpose + f32->bf16:  in[R,C] f32  ->  out[C,R] bf16
// ---------------------------------------------------------------------------
__global__ __launch_bounds__(256) void transpose_w(const float* __restrict__ in,
                                                   bf16* __restrict__ out, int R, int C)
{
    __shared__ float t[32][33];
    int c0 = blockIdx.x * 32, r0 = blockIdx.y * 32;
    int tx = threadIdx.x, ty = threadIdx.y;
    for (int j = ty; j < 32; j += 8) {
        int r = r0 + j, c = c0 + tx;
        t[j][tx] = (r < R && c < C) ? in[(size_t)r * C + c] : 0.f;
    }
    __syncthreads();
    for (int j = ty; j < 32; j += 8) {
        int c = c0 + j, r = r0 + tx;
        if (c < C && r < R) out[(size_t)c * R + r] = __float2bfloat16(t[tx][j]);
    }
}

// vT[h][d][s] = kv[s][h*256 + 128 + d]   (bf16 transpose per head)
__global__ __launch_bounds__(256) void transpose_v(const bf16* __restrict__ kv,
                                                   bf16* __restrict__ vT)
{
    __shared__ bf16 t[32][33];
    int h = blockIdx.z;
    int d0 = blockIdx.x * 32, s0 = blockIdx.y * 32;
    int tx = threadIdx.x, ty = threadIdx.y;
    for (int j = ty; j < 32; j += 8)
        t[j][tx] = kv[(size_t)(s0 + j) * (H_*256) + h*256 + 128 + d0 + tx];
    __syncthreads();
    for (int j = ty; j < 32; j += 8)
        vT[((size_t)h * VD_ + d0 + j) * S_ + s0 + tx] = t[tx][j];
}

// ---------------------------------------------------------------------------
// RMSNorm: f32 in (strided) -> bf16 out
// ---------------------------------------------------------------------------
__global__ __launch_bounds__(256) void rmsnorm_k(const float* __restrict__ in,
                                                 const float* __restrict__ w,
                                                 bf16* __restrict__ out,
                                                 int cols, int istride, int ostride)
{
    int row = blockIdx.x, tid = threadIdx.x;
    const float* ip = in + (size_t)row * istride;
    bf16* op = out + (size_t)row * ostride;
    float ss = 0.f;
    for (int c = tid; c < cols; c += 256) { float v = ip[c]; ss = fmaf(v, v, ss); }
    for (int o = 32; o > 0; o >>= 1) ss += __shfl_down(ss, o, 64);
    __shared__ float red[4];
    __shared__ float s_sc;
    int wave = tid >> 6, lane = tid & 63;
    if (lane == 0) red[wave] = ss;
    __syncthreads();
    if (tid == 0) s_sc = rsqrtf((red[0]+red[1]+red[2]+red[3]) / (float)cols + EPS_);
    __syncthreads();
    float sc = s_sc;
    for (int c = tid; c < cols; c += 256)
        op[c] = __float2bfloat16(ip[c] * sc * w[c]);
}

// ---------------------------------------------------------------------------
// RoPE constants: inv_i = exp(-i * 2*ln(10000)/64)
// out[i]    = x[2i]*cos - x[2i+1]*sin ; out[32+i] = x[2i+1]*cos + x[2i]*sin
// ---------------------------------------------------------------------------
#define ROPE_LC 0.28782313662425575f

// qf[h][s][0:192] from q[s][h*192 + ...], pre-scaled by 1/sqrt(192)
__global__ __launch_bounds__(192) void build_q(const bf16* __restrict__ q,
                                               bf16* __restrict__ qf)
{
    int s = blockIdx.x, h = blockIdx.y, t = threadIdx.x;
    const float scale = 0.07216878364870323f;  // 1/sqrt(192)
    const bf16* src = q + (size_t)s * (H_*QKD_) + h * QKD_;
    bf16* dst = qf + ((size_t)h * S_ + s) * QKD_;
    if (t < NOPE_) {
        dst[t] = __float2bfloat16(__bfloat162float(src[t]) * scale);
    } else {
        int i = (t - NOPE_) & 31;
        bool hi = (t - NOPE_) >= 32;
        float a = __bfloat162float(src[NOPE_ + 2*i]);
        float b = __bfloat162float(src[NOPE_ + 2*i + 1]);
        float inv = __expf(-(float)i * ROPE_LC);
        float f = (float)s * inv, c, sn;
        sincosf(f, &sn, &c);
        float v = hi ? (b * c + a * sn) : (a * c - b * sn);
        dst[t] = __float2bfloat16(v * scale);
    }
}

// kf[h][s][0:192]: nope from kv[s][h*256+d]; roped pe (shared) from kva[s][512+...]
__global__ __launch_bounds__(192) void build_k(const bf16* __restrict__ kv,
                                               const float* __restrict__ kva,
                                               bf16* __restrict__ kf)
{
    int s = blockIdx.x, h = blockIdx.y, t = threadIdx.x;
    const bf16* src = kv + (size_t)s * (H_*256) + h * 256;
    bf16* dst = kf + ((size_t)h * S_ + s) * QKD_;
    if (t < NOPE_) {
        dst[t] = src[t];
    } else {
        int i = (t - NOPE_) & 31;
        bool hi = (t - NOPE_) >= 32;
        const float* pe = kva + (size_t)s * (KVR_ + ROPE_) + KVR_;
        float a = pe[2*i], b = pe[2*i + 1];
        float inv = __expf(-(float)i * ROPE_LC);
        float f = (float)s * inv, c, sn;
        sincosf(f, &sn, &c);
        dst[t] = __float2bfloat16(hi ? (b * c + a * sn) : (a * c - b * sn));
    }
}

// ---------------------------------------------------------------------------
// Causal softmax in-place on bf16 scores row; zeros pad to next 128 boundary
// (PV kernel's causal K-limit only ever reads up to that boundary).
// ---------------------------------------------------------------------------
__global__ __launch_bounds__(256) void softmax_k(bf16* __restrict__ Sc)
{
    int q = blockIdx.x, h = blockIdx.y;
    bf16* row = Sc + ((size_t)h * S_ + q) * S_;
    int n = q + 1;
    int tid = threadIdx.x, lane = tid & 63, wave = tid >> 6;
    __shared__ float red[4];
    __shared__ float bc;
    float mx = -3.0e38f;
    for (int c = tid; c < n; c += 256) mx = fmaxf(mx, __bfloat162float(row[c]));
    for (int o = 32; o > 0; o >>= 1) mx = fmaxf(mx, __shfl_down(mx, o, 64));
    if (lane == 0) red[wave] = mx;
    __syncthreads();
    if (tid == 0) bc = fmaxf(fmaxf(red[0], red[1]), fmaxf(red[2], red[3]));
    __syncthreads();
    float m = bc;
    float sum = 0.f;
    for (int c = tid; c < n; c += 256) {
        float e = __expf(__bfloat162float(row[c]) - m);
        sum += e;
        row[c] = __float2bfloat16(e);
    }
    for (int o = 32; o > 0; o >>= 1) sum += __shfl_down(sum, o, 64);
    __syncthreads();
    if (lane == 0) red[wave] = sum;
    __syncthreads();
    if (tid == 0) bc = 1.0f / (red[0] + red[1] + red[2] + red[3]);
    __syncthreads();
    float inv = bc;
    for (int c = tid; c < n; c += 256)
        row[c] = __float2bfloat16(__bfloat162float(row[c]) * inv);
    int klim = (q / 128 + 1) * 128;
    for (int c = n + tid; c < klim; c += 256) row[c] = __float2bfloat16(0.f);
}

// ---------------------------------------------------------------------------
static inline void gemm(hipStream_t st, const bf16* A, const bf16* BT, void* C,
                        const float* bias, const float* res,
                        int M, int N, int K, int lda, int ldb, int ldc,
                        long long sA, long long sB, long long sC,
                        int batch, int mode, int causal)
{
    dim3 g((N + 127) / 128, M / 128, batch);
    gemm_k<<<g, 256, 0, st>>>(A, BT, C, bias, res, M, N, K, lda, ldb, ldc,
                              sA, sB, sC, mode, causal);
}

static inline void transw(hipStream_t st, const float* in, bf16* out, int R, int C)
{
    dim3 g((C + 31) / 32, (R + 31) / 32);
    transpose_w<<<g, dim3(32, 8), 0, st>>>(in, out, R, C);
}

extern "C" void kernel_launch(void* const* d_in, const int* in_sizes, int n_in,
                              void* d_out, int out_size, void* d_ws, size_t ws_size,
                              hipStream_t stream)
{
    const float* x        = (const float*)d_in[0];
    const float* norm1_w  = (const float*)d_in[1];
    const float* q_a_w    = (const float*)d_in[2];
    const float* q_a_ln_w = (const float*)d_in[3];
    const float* q_b_w    = (const float*)d_in[4];
    const float* kv_a_w   = (const float*)d_in[5];
    const float* kv_a_ln_w= (const float*)d_in[6];
    const float* kv_b_w   = (const float*)d_in[7];
    const float* o_w      = (const float*)d_in[8];
    const float* norm2_w  = (const float*)d_in[9];
    const float* ffn_w1   = (const float*)d_in[10];
    const float* ffn_b1   = (const float*)d_in[11];
    const float* ffn_w2   = (const float*)d_in[12];
    const float* ffn_b2   = (const float*)d_in[13];
    float* out = (float*)d_out;

    // ---- workspace layout (all 256B aligned), ~262 MB ----
    size_t off = 0;
    auto alloc = [&](size_t bytes) -> void* {
        void* p = (char*)d_ws + off;
        off += (bytes + 255) & ~(size_t)255;
        return p;
    };
    bf16*  hs    = (bf16*) alloc((size_t)S_*D_*2);
    bf16*  wqaT  = (bf16*) alloc((size_t)QR_*D_*2);
    bf16*  wqbT  = (bf16*) alloc((size_t)(H_*QKD_)*QR_*2);
    bf16*  wkvaT = (bf16*) alloc((size_t)(KVR_+ROPE_)*D_*2);
    bf16*  wkvbT = (bf16*) alloc((size_t)(H_*(NOPE_+VD_))*KVR_*2);
    bf16*  woT   = (bf16*) alloc((size_t)D_*(H_*VD_)*2);
    bf16*  wf1T  = (bf16*) alloc((size_t)(4*D_)*D_*2);
    bf16*  wf2T  = (bf16*) alloc((size_t)D_*(4*D_)*2);
    float* qa    = (float*)alloc((size_t)S_*QR_*4);            // later reused as x2
    bf16*  qln   = (bf16*) alloc((size_t)S_*QR_*2);
    bf16*  qb    = (bf16*) alloc((size_t)S_*H_*QKD_*2);        // later reused as h2
    float* kva   = (float*)alloc((size_t)S_*(KVR_+ROPE_)*4);
    bf16*  kvln  = (bf16*) alloc((size_t)S_*KVR_*2);
    bf16*  kvb   = (bf16*) alloc((size_t)S_*H_*(NOPE_+VD_)*2); // later reused as ao
    bf16*  qf    = (bf16*) alloc((size_t)H_*S_*QKD_*2);
    bf16*  kf    = (bf16*) alloc((size_t)H_*S_*QKD_*2);
    bf16*  vT    = (bf16*) alloc((size_t)H_*VD_*S_*2);
    bf16*  Sc    = (bf16*) alloc((size_t)8*S_*S_*2);           // 8 heads/group; reused as a1
    // aliases (lifetimes disjoint)
    float* x2 = qa;        // 16.8MB over qa+qln (18.9MB)
    bf16*  h2 = qb;
    bf16*  ao = kvb;
    bf16*  a1 = Sc;

    // ---- weight transposes (f32 -> bf16, N-major for GEMM BT operand) ----
    transw(stream, q_a_w,  wqaT,  D_,  QR_);
    transw(stream, q_b_w,  wqbT,  QR_, H_*QKD_);
    transw(stream, kv_a_w, wkvaT, D_,  KVR_+ROPE_);
    transw(stream, kv_b_w, wkvbT, KVR_, H_*(NOPE_+VD_));
    transw(stream, o_w,    woT,   H_*VD_, D_);
    transw(stream, ffn_w1, wf1T,  D_,  4*D_);
    transw(stream, ffn_w2, wf2T,  4*D_, D_);

    // ---- pre-attention pipeline ----
    rmsnorm_k<<<S_, 256, 0, stream>>>(x, norm1_w, hs, D_, D_, D_);
    gemm(stream, hs, wqaT, qa, nullptr, nullptr, S_, QR_, D_, D_, D_, QR_, 0,0,0, 1, 0, 0);
    rmsnorm_k<<<S_, 256, 0, stream>>>(qa, q_a_ln_w, qln, QR_, QR_, QR_);
    gemm(stream, qln, wqbT, qb, nullptr, nullptr, S_, H_*QKD_, QR_, QR_, QR_, H_*QKD_, 0,0,0, 1, 1, 0);
    gemm(stream, hs, wkvaT, kva, nullptr, nullptr, S_, KVR_+ROPE_, D_, D_, D_, KVR_+ROPE_, 0,0,0, 1, 0, 0);
    rmsnorm_k<<<S_, 256, 0, stream>>>(kva, kv_a_ln_w, kvln, KVR_, KVR_+ROPE_, KVR_);
    gemm(stream, kvln, wkvbT, kvb, nullptr, nullptr, S_, H_*(NOPE_+VD_), KVR_, KVR_, KVR_, H_*(NOPE_+VD_), 0,0,0, 1, 1, 0);

    build_q<<<dim3(S_, H_), 192, 0, stream>>>(qb, qf);
    build_k<<<dim3(S_, H_), 192, 0, stream>>>(kvb, kva, kf);
    transpose_v<<<dim3(VD_/32, S_/32, H_), dim3(32, 8), 0, stream>>>(kvb, vT);

    // ---- attention: 2 groups of 8 heads through one 8-head score buffer ----
    for (int g = 0; g < 2; ++g) {
        const bf16* qfg = qf + (size_t)g * 8 * S_ * QKD_;
        const bf16* kfg = kf + (size_t)g * 8 * S_ * QKD_;
        const bf16* vTg = vT + (size_t)g * 8 * VD_ * S_;
        // scores = (q/sqrt(d)) @ k^T, bf16 out, skip above-diagonal tiles
        gemm(stream, qfg, kfg, Sc, nullptr, nullptr,
             S_, S_, QKD_, QKD_, QKD_, S_,
             (long long)S_*QKD_, (long long)S_*QKD_, (long long)S_*S_, 8, 1, 1);
        softmax_k<<<dim3(S_, 8), 256, 0, stream>>>(Sc);
        // out = P @ V  (K limited to causal boundary per row-tile)
        gemm(stream, Sc, vTg, ao + (size_t)g * 8 * VD_, nullptr, nullptr,
             S_, VD_, S_, S_, S_, H_*VD_,
             (long long)S_*S_, (long long)VD_*S_, (long long)VD_, 8, 1, 2);
    }

    // ---- o-projection + residual -> x2 (f32) ----
    gemm(stream, ao, woT, x2, nullptr, x, S_, D_, H_*VD_, H_*VD_, H_*VD_, D_, 0,0,0, 1, 2, 0);

    // ---- FFN ----
    rmsnorm_k<<<S_, 256, 0, stream>>>(x2, norm2_w, h2, D_, D_, D_);
    gemm(stream, h2, wf1T, a1, ffn_b1, nullptr, S_, 4*D_, D_, D_, D_, 4*D_, 0,0,0, 1, 3, 0);
    gemm(stream, a1, wf2T, out, ffn_b2, x2, S_, D_, 4*D_, 4*D_, 4*D_, D_, 0,0,0, 1, 4, 0);
}

// Round 2
// 1107.132 us; speedup vs baseline: 1.1800x; 1.1800x over previous
//
#include <hip/hip_runtime.h>
#include <hip/hip_bf16.h>

typedef __hip_bfloat16 bf16;
using bf16x8 = __attribute__((ext_vector_type(8))) __bf16;
using f32x4  = __attribute__((ext_vector_type(4))) float;

#define S_   2048
#define D_   2048
#define H_   16
#define QR_  1536
#define KVR_ 512
#define NOPE_ 128
#define ROPE_ 64
#define VD_  128
#define QKD_ 192
#define EPS_ 1e-5f

// async global->LDS, 16B per lane; LDS dest = wave-uniform base + lane*16
#define GLDS16(g, l) \
    __builtin_amdgcn_global_load_lds((const __attribute__((address_space(1))) void*)(g), \
                                     (__attribute__((address_space(3))) void*)(l), 16, 0, 0)

// ---------------------------------------------------------------------------
// bf16 MFMA GEMM: C[M,N] = A[M,K] @ B[K,N], B given as BT[N,K].
// 256 thr = 4 waves; tile 128x128; wave does 64x64 (4x4 of 16x16x32 bf16).
// m97-style staging: global_load_lds width=16 into unpadded 128x32 LDS tiles.
// mode: 0=f32 store, 1=bf16 store, 2=f32 +res, 3=bf16 gelu(x+bias),
//       4=f32 +bias+res, 5=f32 atomicAdd (split-K partials)
// causal: 0=none, 1=skip tiles above diagonal (scores), 2=K limited to diag (PV)
// ksplit/kchunk: split-K; grid.z packs batch*ksplit.
// ---------------------------------------------------------------------------
__global__ __launch_bounds__(256) void gemm_k(
    const bf16* __restrict__ A, const bf16* __restrict__ BT, void* __restrict__ Cv,
    const float* __restrict__ bias, const float* __restrict__ res,
    int M, int N, int K, int lda, int ldb, int ldc,
    long long strideA, long long strideB, long long strideC,
    int mode, int causal, int ksplit, int kchunk)
{
    int bn = blockIdx.x, bm = blockIdx.y, bz = blockIdx.z;
    int kc = 0;
    if (ksplit > 1) { kc = bz % ksplit; bz /= ksplit; }
    if (causal == 1 && bn > bm) return;
    A  += (size_t)bz * strideA;
    BT += (size_t)bz * strideB;

    int k_end = K;
    if (causal == 2) { int kl = (bm + 1) * 128; if (kl < k_end) k_end = kl; }
    int k_begin = kc * kchunk;
    if (k_begin + kchunk < k_end) k_end = k_begin + kchunk;
    if (k_begin >= k_end) return;

    __shared__ bf16 sA[128 * 32];
    __shared__ bf16 sB[128 * 32];

    int tid  = threadIdx.x;
    int lane = tid & 63, wave = tid >> 6;
    int wr = wave >> 1, wc = wave & 1;     // wave's 64x64 quadrant
    int fr = lane & 15, fq = lane >> 4;    // fragment row / k-quad

    int row0 = bm * 128, col0 = bn * 128;

    // staging: wave w covers rows [w*16, w*16+16) and +64; lane L -> row w*16+L/4, k-off (L&3)*8
    int srow = wave * 16 + (lane >> 2);
    int sko  = (lane & 3) * 8;
    const bf16* ga0 = A + (size_t)(row0 + srow) * lda + sko;
    const bf16* ga1 = ga0 + (size_t)64 * lda;
    int bn0 = col0 + srow;      if (bn0 > N - 1) bn0 = N - 1;   // clamp (cols >= N discarded)
    int bn1 = col0 + srow + 64; if (bn1 > N - 1) bn1 = N - 1;
    const bf16* gb0 = BT + (size_t)bn0 * ldb + sko;
    const bf16* gb1 = BT + (size_t)bn1 * ldb + sko;
    bf16* lA0 = &sA[(wave * 16) * 32];
    bf16* lA1 = &sA[(64 + wave * 16) * 32];
    bf16* lB0 = &sB[(wave * 16) * 32];
    bf16* lB1 = &sB[(64 + wave * 16) * 32];

    f32x4 acc[4][4] = {};

    for (int k0 = k_begin; k0 < k_end; k0 += 32) {
        GLDS16(ga0 + k0, lA0);
        GLDS16(ga1 + k0, lA1);
        GLDS16(gb0 + k0, lB0);
        GLDS16(gb1 + k0, lB1);
        __syncthreads();
        bf16x8 af[4], bv[4];
        #pragma unroll
        for (int i = 0; i < 4; ++i)
            af[i] = *(const bf16x8*)&sA[(wr*64 + i*16 + fr) * 32 + fq*8];
        #pragma unroll
        for (int j = 0; j < 4; ++j)
            bv[j] = *(const bf16x8*)&sB[(wc*64 + j*16 + fr) * 32 + fq*8];
        #pragma unroll
        for (int i = 0; i < 4; ++i)
            #pragma unroll
            for (int j = 0; j < 4; ++j)
                acc[i][j] = __builtin_amdgcn_mfma_f32_16x16x32_bf16(af[i], bv[j], acc[i][j], 0, 0, 0);
        __syncthreads();
    }

    // epilogue: D[row=(lane>>4)*4+r][col=lane&15] per 16x16 tile (verified m89 layout)
    #pragma unroll
    for (int i = 0; i < 4; ++i) {
        #pragma unroll
        for (int j = 0; j < 4; ++j) {
            int gc = col0 + wc*64 + j*16 + fr;
            if (gc >= N) continue;
            #pragma unroll
            for (int r = 0; r < 4; ++r) {
                int gr = row0 + wr*64 + i*16 + fq*4 + r;
                float v = acc[i][j][r];
                size_t off = (size_t)bz * strideC + (size_t)gr * ldc + gc;
                if (mode == 0) {
                    ((float*)Cv)[off] = v;
                } else if (mode == 1) {
                    ((bf16*)Cv)[off] = __float2bfloat16(v);
                } else if (mode == 2) {
                    ((float*)Cv)[off] = v + res[(size_t)gr * ldc + gc];
                } else if (mode == 3) {
                    float t = v + bias[gc];
                    t = 0.5f * t * (1.0f + erff(t * 0.70710678118654752f));
                    ((bf16*)Cv)[off] = __float2bfloat16(t);
                } else if (mode == 4) {
                    ((float*)Cv)[off] = v + bias[gc] + res[(size_t)gr * ldc + gc];
                } else {
                    atomicAdd(&((float*)Cv)[off], v);
                }
            }
        }
    }
}

// ---------------------------------------------------------------------------
// dst = (src? src : 0) + (bias? bias[col] : 0), float4-vectorized
// ---------------------------------------------------------------------------
__global__ __launch_bounds__(256) void fill_add_k(float* __restrict__ dst,
        const float* __restrict__ src, const float* __restrict__ bias,
        long long n4, long long cols4)
{
    long long i = (long long)blockIdx.x * 256 + threadIdx.x;
    long long stride = (long long)gridDim.x * 256;
    for (; i < n4; i += stride) {
        float4 v = src ? ((const float4*)src)[i] : float4{0.f, 0.f, 0.f, 0.f};
        if (bias) {
            float4 b = ((const float4*)bias)[i % cols4];
            v.x += b.x; v.y += b.y; v.z += b.z; v.w += b.w;
        }
        ((float4*)dst)[i] = v;
    }
}

__global__ __launch_bounds__(256) void f32_to_bf16_k(const float* __restrict__ in,
        bf16* __restrict__ out, long long n4)
{
    long long i = (long long)blockIdx.x * 256 + threadIdx.x;
    long long stride = (long long)gridDim.x * 256;
    for (; i < n4; i += stride) {
        float4 v = ((const float4*)in)[i];
        ushort4 o;
        bf16 t0 = __float2bfloat16(v.x); o.x = *(unsigned short*)&t0;
        bf16 t1 = __float2bfloat16(v.y); o.y = *(unsigned short*)&t1;
        bf16 t2 = __float2bfloat16(v.z); o.z = *(unsigned short*)&t2;
        bf16 t3 = __float2bfloat16(v.w); o.w = *(unsigned short*)&t3;
        ((ushort4*)out)[i] = o;
    }
}

// ---------------------------------------------------------------------------
// Weight transpose + f32->bf16:  in[R,C] f32  ->  out[C,R] bf16
// ---------------------------------------------------------------------------
__global__ __launch_bounds__(256) void transpose_w(const float* __restrict__ in,
                                                   bf16* __restrict__ out, int R, int C)
{
    __shared__ float t[32][33];
    int c0 = blockIdx.x * 32, r0 = blockIdx.y * 32;
    int tx = threadIdx.x, ty = threadIdx.y;
    for (int j = ty; j < 32; j += 8) {
        int r = r0 + j, c = c0 + tx;
        t[j][tx] = (r < R && c < C) ? in[(size_t)r * C + c] : 0.f;
    }
    __syncthreads();
    for (int j = ty; j < 32; j += 8) {
        int c = c0 + j, r = r0 + tx;
        if (c < C && r < R) out[(size_t)c * R + r] = __float2bfloat16(t[tx][j]);
    }
}

// vT[h][d][s] = kv[s][h*256 + 128 + d]   (bf16 transpose per head)
__global__ __launch_bounds__(256) void transpose_v(const bf16* __restrict__ kv,
                                                   bf16* __restrict__ vT)
{
    __shared__ bf16 t[32][33];
    int h = blockIdx.z;
    int d0 = blockIdx.x * 32, s0 = blockIdx.y * 32;
    int tx = threadIdx.x, ty = threadIdx.y;
    for (int j = ty; j < 32; j += 8)
        t[j][tx] = kv[(size_t)(s0 + j) * (H_*256) + h*256 + 128 + d0 + tx];
    __syncthreads();
    for (int j = ty; j < 32; j += 8)
        vT[((size_t)h * VD_ + d0 + j) * S_ + s0 + tx] = t[tx][j];
}

// ---------------------------------------------------------------------------
// RMSNorm: f32 in (strided) -> bf16 out
// ---------------------------------------------------------------------------
__global__ __launch_bounds__(256) void rmsnorm_k(const float* __restrict__ in,
                                                 const float* __restrict__ w,
                                                 bf16* __restrict__ out,
                                                 int cols, int istride, int ostride)
{
    int row = blockIdx.x, tid = threadIdx.x;
    const float* ip = in + (size_t)row * istride;
    bf16* op = out + (size_t)row * ostride;
    float ss = 0.f;
    for (int c = tid; c < cols; c += 256) { float v = ip[c]; ss = fmaf(v, v, ss); }
    for (int o = 32; o > 0; o >>= 1) ss += __shfl_down(ss, o, 64);
    __shared__ float red[4];
    __shared__ float s_sc;
    int wave = tid >> 6, lane = tid & 63;
    if (lane == 0) red[wave] = ss;
    __syncthreads();
    if (tid == 0) s_sc = rsqrtf((red[0]+red[1]+red[2]+red[3]) / (float)cols + EPS_);
    __syncthreads();
    float sc = s_sc;
    for (int c = tid; c < cols; c += 256)
        op[c] = __float2bfloat16(ip[c] * sc * w[c]);
}

// ---------------------------------------------------------------------------
// RoPE: inv_i = exp(-i * 2*ln(10000)/64)
// out[i] = x[2i]*cos - x[2i+1]*sin ; out[32+i] = x[2i+1]*cos + x[2i]*sin
// ---------------------------------------------------------------------------
#define ROPE_LC 0.28782313662425575f

__global__ __launch_bounds__(192) void build_q(const bf16* __restrict__ q,
                                               bf16* __restrict__ qf)
{
    int s = blockIdx.x, h = blockIdx.y, t = threadIdx.x;
    const float scale = 0.07216878364870323f;  // 1/sqrt(192)
    const bf16* src = q + (size_t)s * (H_*QKD_) + h * QKD_;
    bf16* dst = qf + ((size_t)h * S_ + s) * QKD_;
    if (t < NOPE_) {
        dst[t] = __float2bfloat16(__bfloat162float(src[t]) * scale);
    } else {
        int i = (t - NOPE_) & 31;
        bool hi = (t - NOPE_) >= 32;
        float a = __bfloat162float(src[NOPE_ + 2*i]);
        float b = __bfloat162float(src[NOPE_ + 2*i + 1]);
        float inv = __expf(-(float)i * ROPE_LC);
        float f = (float)s * inv, c, sn;
        sincosf(f, &sn, &c);
        float v = hi ? (b * c + a * sn) : (a * c - b * sn);
        dst[t] = __float2bfloat16(v * scale);
    }
}

__global__ __launch_bounds__(192) void build_k(const bf16* __restrict__ kv,
                                               const float* __restrict__ kva,
                                               bf16* __restrict__ kf)
{
    int s = blockIdx.x, h = blockIdx.y, t = threadIdx.x;
    const bf16* src = kv + (size_t)s * (H_*256) + h * 256;
    bf16* dst = kf + ((size_t)h * S_ + s) * QKD_;
    if (t < NOPE_) {
        dst[t] = src[t];
    } else {
        int i = (t - NOPE_) & 31;
        bool hi = (t - NOPE_) >= 32;
        const float* pe = kva + (size_t)s * (KVR_ + ROPE_) + KVR_;
        float a = pe[2*i], b = pe[2*i + 1];
        float inv = __expf(-(float)i * ROPE_LC);
        float f = (float)s * inv, c, sn;
        sincosf(f, &sn, &c);
        dst[t] = __float2bfloat16(hi ? (b * c + a * sn) : (a * c - b * sn));
    }
}

// ---------------------------------------------------------------------------
// Causal softmax in-place on bf16 score rows; zero-pads to next 128 boundary.
// ---------------------------------------------------------------------------
__global__ __launch_bounds__(256) void softmax_k(bf16* __restrict__ Sc)
{
    int q = blockIdx.x, h = blockIdx.y;
    bf16* row = Sc + ((size_t)h * S_ + q) * S_;
    int n = q + 1;
    int tid = threadIdx.x, lane = tid & 63, wave = tid >> 6;
    __shared__ float red[4];
    __shared__ float bc;
    float mx = -3.0e38f;
    for (int c = tid; c < n; c += 256) mx = fmaxf(mx, __bfloat162float(row[c]));
    for (int o = 32; o > 0; o >>= 1) mx = fmaxf(mx, __shfl_down(mx, o, 64));
    if (lane == 0) red[wave] = mx;
    __syncthreads();
    if (tid == 0) bc = fmaxf(fmaxf(red[0], red[1]), fmaxf(red[2], red[3]));
    __syncthreads();
    float m = bc;
    float sum = 0.f;
    for (int c = tid; c < n; c += 256) {
        float e = __expf(__bfloat162float(row[c]) - m);
        sum += e;
        row[c] = __float2bfloat16(e);
    }
    for (int o = 32; o > 0; o >>= 1) sum += __shfl_down(sum, o, 64);
    __syncthreads();
    if (lane == 0) red[wave] = sum;
    __syncthreads();
    if (tid == 0) bc = 1.0f / (red[0] + red[1] + red[2] + red[3]);
    __syncthreads();
    float inv = bc;
    for (int c = tid; c < n; c += 256)
        row[c] = __float2bfloat16(__bfloat162float(row[c]) * inv);
    int klim = (q / 128 + 1) * 128;
    for (int c = n + tid; c < klim; c += 256) row[c] = __float2bfloat16(0.f);
}

// ---------------------------------------------------------------------------
static inline void gemm(hipStream_t st, const bf16* A, const bf16* BT, void* C,
                        const float* bias, const float* res,
                        int M, int N, int K, int lda, int ldb, int ldc,
                        long long sA, long long sB, long long sC,
                        int batch, int mode, int causal, int ksplit = 1, int kchunk = 0)
{
    if (kchunk == 0) kchunk = K;
    dim3 g((N + 127) / 128, M / 128, batch * ksplit);
    gemm_k<<<g, 256, 0, st>>>(A, BT, C, bias, res, M, N, K, lda, ldb, ldc,
                              sA, sB, sC, mode, causal, ksplit, kchunk);
}

static inline void transw(hipStream_t st, const float* in, bf16* out, int R, int C)
{
    dim3 g((C + 31) / 32, (R + 31) / 32);
    transpose_w<<<g, dim3(32, 8), 0, st>>>(in, out, R, C);
}

extern "C" void kernel_launch(void* const* d_in, const int* in_sizes, int n_in,
                              void* d_out, int out_size, void* d_ws, size_t ws_size,
                              hipStream_t stream)
{
    const float* x        = (const float*)d_in[0];
    const float* norm1_w  = (const float*)d_in[1];
    const float* q_a_w    = (const float*)d_in[2];
    const float* q_a_ln_w = (const float*)d_in[3];
    const float* q_b_w    = (const float*)d_in[4];
    const float* kv_a_w   = (const float*)d_in[5];
    const float* kv_a_ln_w= (const float*)d_in[6];
    const float* kv_b_w   = (const float*)d_in[7];
    const float* o_w      = (const float*)d_in[8];
    const float* norm2_w  = (const float*)d_in[9];
    const float* ffn_w1   = (const float*)d_in[10];
    const float* ffn_b1   = (const float*)d_in[11];
    const float* ffn_w2   = (const float*)d_in[12];
    const float* ffn_b2   = (const float*)d_in[13];
    float* out = (float*)d_out;

    // ---- workspace layout (~262 MB) ----
    size_t off = 0;
    auto alloc = [&](size_t bytes) -> void* {
        void* p = (char*)d_ws + off;
        off += (bytes + 255) & ~(size_t)255;
        return p;
    };
    bf16*  hs    = (bf16*) alloc((size_t)S_*D_*2);
    bf16*  wqaT  = (bf16*) alloc((size_t)QR_*D_*2);
    bf16*  wqbT  = (bf16*) alloc((size_t)(H_*QKD_)*QR_*2);
    bf16*  wkvaT = (bf16*) alloc((size_t)(KVR_+ROPE_)*D_*2);
    bf16*  wkvbT = (bf16*) alloc((size_t)(H_*(NOPE_+VD_))*KVR_*2);
    bf16*  woT   = (bf16*) alloc((size_t)D_*(H_*VD_)*2);
    bf16*  wf1T  = (bf16*) alloc((size_t)(4*D_)*D_*2);
    bf16*  wf2T  = (bf16*) alloc((size_t)D_*(4*D_)*2);
    float* qa    = (float*)alloc((size_t)S_*QR_*4);
    bf16*  qln   = (bf16*) alloc((size_t)S_*QR_*2);
    bf16*  qb    = (bf16*) alloc((size_t)S_*H_*QKD_*2);
    float* kva   = (float*)alloc((size_t)S_*(KVR_+ROPE_)*4);
    bf16*  kvln  = (bf16*) alloc((size_t)S_*KVR_*2);
    bf16*  kvb   = (bf16*) alloc((size_t)S_*H_*(NOPE_+VD_)*2);
    bf16*  qf    = (bf16*) alloc((size_t)H_*S_*QKD_*2);
    bf16*  kf    = (bf16*) alloc((size_t)H_*S_*QKD_*2);
    bf16*  vT    = (bf16*) alloc((size_t)H_*VD_*S_*2);
    bf16*  Sc    = (bf16*) alloc((size_t)8*S_*S_*2);
    // aliases (lifetimes disjoint):
    float* x2   = qa;          // 16.8MB over qa+qln (18.9MB), live post-attention
    bf16*  h2   = qb;          // live post-attention
    bf16*  ao   = kvb;         // bf16 attn-out, written post-attention
    bf16*  a1   = Sc;          // ffn activation, post-attention
    float* ao32 = (float*)hs;  // 16.8MB over hs+wqaT+2.1MB of wqbT — all dead pre-attention

    // ---- weight transposes ----
    transw(stream, q_a_w,  wqaT,  D_,  QR_);
    transw(stream, q_b_w,  wqbT,  QR_, H_*QKD_);
    transw(stream, kv_a_w, wkvaT, D_,  KVR_+ROPE_);
    transw(stream, kv_b_w, wkvbT, KVR_, H_*(NOPE_+VD_));
    transw(stream, o_w,    woT,   H_*VD_, D_);
    transw(stream, ffn_w1, wf1T,  D_,  4*D_);
    transw(stream, ffn_w2, wf2T,  4*D_, D_);

    // ---- pre-attention pipeline ----
    rmsnorm_k<<<S_, 256, 0, stream>>>(x, norm1_w, hs, D_, D_, D_);

    fill_add_k<<<512, 256, 0, stream>>>(qa, nullptr, nullptr, (long long)S_*QR_/4, 1);
    gemm(stream, hs, wqaT, qa, nullptr, nullptr, S_, QR_, D_, D_, D_, QR_, 0,0,0, 1, 5, 0, 2, 1024);
    rmsnorm_k<<<S_, 256, 0, stream>>>(qa, q_a_ln_w, qln, QR_, QR_, QR_);
    gemm(stream, qln, wqbT, qb, nullptr, nullptr, S_, H_*QKD_, QR_, QR_, QR_, H_*QKD_, 0,0,0, 1, 1, 0);

    fill_add_k<<<512, 256, 0, stream>>>(kva, nullptr, nullptr, (long long)S_*(KVR_+ROPE_)/4, 1);
    gemm(stream, hs, wkvaT, kva, nullptr, nullptr, S_, KVR_+ROPE_, D_, D_, D_, KVR_+ROPE_, 0,0,0, 1, 5, 0, 4, 512);
    rmsnorm_k<<<S_, 256, 0, stream>>>(kva, kv_a_ln_w, kvln, KVR_, KVR_+ROPE_, KVR_);
    gemm(stream, kvln, wkvbT, kvb, nullptr, nullptr, S_, H_*(NOPE_+VD_), KVR_, KVR_, KVR_, H_*(NOPE_+VD_), 0,0,0, 1, 1, 0);

    build_q<<<dim3(S_, H_), 192, 0, stream>>>(qb, qf);
    build_k<<<dim3(S_, H_), 192, 0, stream>>>(kvb, kva, kf);
    transpose_v<<<dim3(VD_/32, S_/32, H_), dim3(32, 8), 0, stream>>>(kvb, vT);

    // ---- attention: 2 groups of 8 heads; PV split-K into f32 accumulator ----
    fill_add_k<<<512, 256, 0, stream>>>(ao32, nullptr, nullptr, (long long)S_*(H_*VD_)/4, 1);
    for (int g = 0; g < 2; ++g) {
        const bf16* qfg = qf + (size_t)g * 8 * S_ * QKD_;
        const bf16* kfg = kf + (size_t)g * 8 * S_ * QKD_;
        const bf16* vTg = vT + (size_t)g * 8 * VD_ * S_;
        gemm(stream, qfg, kfg, Sc, nullptr, nullptr,
             S_, S_, QKD_, QKD_, QKD_, S_,
             (long long)S_*QKD_, (long long)S_*QKD_, (long long)S_*S_, 8, 1, 1);
        softmax_k<<<dim3(S_, 8), 256, 0, stream>>>(Sc);
        gemm(stream, Sc, vTg, ao32 + (size_t)g * 8 * VD_, nullptr, nullptr,
             S_, VD_, S_, S_, S_, H_*VD_,
             (long long)S_*S_, (long long)VD_*S_, (long long)VD_, 8, 5, 2, 4, 512);
    }
    f32_to_bf16_k<<<512, 256, 0, stream>>>(ao32, ao, (long long)S_*(H_*VD_)/4);

    // ---- o-projection + residual: x2 = x, then += ao @ o_w (split-K 2) ----
    fill_add_k<<<512, 256, 0, stream>>>(x2, x, nullptr, (long long)S_*D_/4, 1);
    gemm(stream, ao, woT, x2, nullptr, nullptr, S_, D_, H_*VD_, H_*VD_, H_*VD_, D_, 0,0,0, 1, 5, 0, 2, 1024);

    // ---- FFN ----
    rmsnorm_k<<<S_, 256, 0, stream>>>(x2, norm2_w, h2, D_, D_, D_);
    gemm(stream, h2, wf1T, a1, ffn_b1, nullptr, S_, 4*D_, D_, D_, D_, 4*D_, 0,0,0, 1, 3, 0);
    fill_add_k<<<512, 256, 0, stream>>>(out, x2, ffn_b2, (long long)S_*D_/4, D_/4);
    gemm(stream, a1, wf2T, out, ffn_b2, x2, S_, D_, 4*D_, 4*D_, 4*D_, D_, 0,0,0, 1, 5, 0, 4, 2048);
}